// Round 2
// baseline (659.260 us; speedup 1.0000x reference)
//
#include <hip/hip_runtime.h>
#include <math.h>

// ---------- common types/helpers ----------
typedef short short8 __attribute__((ext_vector_type(8)));
typedef float float4v __attribute__((ext_vector_type(4)));

__device__ __forceinline__ float b2f(ushort u) {
    unsigned v = ((unsigned)u) << 16; float f; __builtin_memcpy(&f, &v, 4); return f;
}
__device__ __forceinline__ ushort f2b(float f) {
    unsigned v; __builtin_memcpy(&v, &f, 4);
    unsigned r = (v + 0x7fffu + ((v >> 16) & 1u)) >> 16;
    return (ushort)r;
}

// ---------- fp32 -> bf16 convert (optional zero-pad rows) ----------
__global__ void cvt_pad(const float* __restrict__ src, ushort* __restrict__ dst,
                        int src_rows, int cols, int total4) {
    int i = blockIdx.x * 256 + threadIdx.x;
    if (i >= total4) return;
    size_t e = (size_t)i * 4;
    int r = (int)(e / (size_t)cols);
    ushort4 o;
    if (r < src_rows) {
        float4 v = *(const float4*)(src + e);
        o.x = f2b(v.x); o.y = f2b(v.y); o.z = f2b(v.z); o.w = f2b(v.w);
    } else {
        o.x = 0; o.y = 0; o.z = 0; o.w = 0;
    }
    *(ushort4*)(dst + e) = o;
}

// ---------- bf16 GEMM: C(MxN) = A(MxK) @ B(NxK)^T, m97-style ----------
// 128x128 tile, BK=32, 256 threads (4 waves, each 64x64 as 4x4 of 16x16 MFMA)
// f32out=1 -> C is float*, else ushort* (bf16)
__global__ __launch_bounds__(256)
void gemm_bt(const ushort* __restrict__ A, const ushort* __restrict__ B,
             void* __restrict__ Cv, int K, int ldc, int nstore, int f32out) {
    __shared__ ushort sA[128 * 32];
    __shared__ ushort sB[128 * 32];
    const int tid = threadIdx.x;
    const int wave = tid >> 6, lane = tid & 63;
    const int bm = blockIdx.y * 128, bn = blockIdx.x * 128;
    const int wm = (wave >> 1) * 64, wn = (wave & 1) * 64;
    float4v acc[4][4] = {};

    const int srow = wave * 32 + (lane >> 2);
    const int skc = (lane & 3) * 8;
    const ushort* Ag = A + (size_t)(bm + srow) * K + skc;
    const ushort* Bg = B + (size_t)(bn + srow) * K + skc;
    ushort* sAw = sA + (wave * 32) * 32;  // wave-uniform LDS base
    ushort* sBw = sB + (wave * 32) * 32;

    for (int k0 = 0; k0 < K; k0 += 32) {
        __builtin_amdgcn_global_load_lds(
            (const __attribute__((address_space(1))) void*)(Ag + k0),
            (__attribute__((address_space(3))) void*)sAw, 16, 0, 0);
        __builtin_amdgcn_global_load_lds(
            (const __attribute__((address_space(1))) void*)(Ag + (size_t)16 * K + k0),
            (__attribute__((address_space(3))) void*)(sAw + 16 * 32), 16, 0, 0);
        __builtin_amdgcn_global_load_lds(
            (const __attribute__((address_space(1))) void*)(Bg + k0),
            (__attribute__((address_space(3))) void*)sBw, 16, 0, 0);
        __builtin_amdgcn_global_load_lds(
            (const __attribute__((address_space(1))) void*)(Bg + (size_t)16 * K + k0),
            (__attribute__((address_space(3))) void*)(sBw + 16 * 32), 16, 0, 0);
        __syncthreads();
        short8 af[4], bfr[4];
#pragma unroll
        for (int i = 0; i < 4; ++i) {
            af[i]  = *(const short8*)(sA + (wm + i * 16 + (lane & 15)) * 32 + (lane >> 4) * 8);
            bfr[i] = *(const short8*)(sB + (wn + i * 16 + (lane & 15)) * 32 + (lane >> 4) * 8);
        }
#pragma unroll
        for (int i = 0; i < 4; ++i)
#pragma unroll
            for (int j = 0; j < 4; ++j)
                acc[i][j] = __builtin_amdgcn_mfma_f32_16x16x32_bf16(af[i], bfr[j], acc[i][j], 0, 0, 0);
        __syncthreads();
    }
#pragma unroll
    for (int i = 0; i < 4; ++i) {
        int row0 = bm + wm + i * 16 + (lane >> 4) * 4;
#pragma unroll
        for (int j = 0; j < 4; ++j) {
            int col = bn + wn + j * 16 + (lane & 15);
            if (col < nstore) {
                if (f32out) {
                    float* C = (float*)Cv;
#pragma unroll
                    for (int r = 0; r < 4; ++r)
                        C[(size_t)(row0 + r) * ldc + col] = acc[i][j][r];
                } else {
                    ushort* C = (ushort*)Cv;
#pragma unroll
                    for (int r = 0; r < 4; ++r)
                        C[(size_t)(row0 + r) * ldc + col] = f2b(acc[i][j][r]);
                }
            }
        }
    }
}

// ---------- rmsnorm (in-place, one block per row) ----------
__global__ void rmsnorm_inplace(ushort* __restrict__ d, const float* __restrict__ w, int cols) {
    int row = blockIdx.x, tid = threadIdx.x;
    ushort* p = d + (size_t)row * cols;
    float ss = 0.f;
    for (int i = tid; i < cols; i += 256) { float v = b2f(p[i]); ss += v * v; }
#pragma unroll
    for (int off = 32; off >= 1; off >>= 1) ss += __shfl_xor(ss, off);
    __shared__ float red[4];
    if ((tid & 63) == 0) red[tid >> 6] = ss;
    __syncthreads();
    float tot = red[0] + red[1] + red[2] + red[3];
    float rs = rsqrtf(tot / (float)cols + 1e-6f);
    for (int i = tid; i < cols; i += 256) p[i] = f2b(b2f(p[i]) * rs * w[i]);
}

// ---------- kv norm (cols 0..512) + k_pe rope (cols 512..576) ----------
__global__ void kvnorm_rope(const ushort* __restrict__ kvraw, const float* __restrict__ w,
                            const float* __restrict__ freqs, ushort* __restrict__ kvc,
                            ushort* __restrict__ kpe) {
    int row = blockIdx.x, tid = threadIdx.x;
    int s = row & 2047;
    const ushort* p = kvraw + (size_t)row * 576;
    float v0 = b2f(p[tid]), v1 = b2f(p[tid + 256]);
    float ss = v0 * v0 + v1 * v1;
#pragma unroll
    for (int off = 32; off >= 1; off >>= 1) ss += __shfl_xor(ss, off);
    __shared__ float red[4];
    if ((tid & 63) == 0) red[tid >> 6] = ss;
    __syncthreads();
    float tot = red[0] + red[1] + red[2] + red[3];
    float rs = rsqrtf(tot / 512.f + 1e-6f);
    kvc[(size_t)row * 512 + tid] = f2b(v0 * rs * w[tid]);
    kvc[(size_t)row * 512 + tid + 256] = f2b(v1 * rs * w[tid + 256]);
    if (tid < 32) {
        float re = b2f(p[512 + 2 * tid]), im = b2f(p[512 + 2 * tid + 1]);
        float cs = freqs[(s * 32 + tid) * 2], sn = freqs[(s * 32 + tid) * 2 + 1];
        kpe[(size_t)row * 64 + 2 * tid] = f2b(re * cs - im * sn);
        kpe[(size_t)row * 64 + 2 * tid + 1] = f2b(re * sn + im * cs);
    }
}

// ---------- rope on q_pe (last 64 of each 192-dim head) ----------
__global__ void qrope(ushort* __restrict__ q, const float* __restrict__ freqs) {
    int idx = blockIdx.x * 256 + threadIdx.x;  // B*S*H*32 = 2097152 total
    int i = idx & 31;
    int h = (idx >> 5) & 15;
    int srow = idx >> 9;
    int s = srow & 2047;
    ushort* p = q + ((size_t)srow * 16 + h) * 192 + 128 + 2 * i;
    float re = b2f(p[0]), im = b2f(p[1]);
    float cs = freqs[(s * 32 + i) * 2], sn = freqs[(s * 32 + i) * 2 + 1];
    p[0] = f2b(re * cs - im * sn);
    p[1] = f2b(re * sn + im * cs);
}

// ---------- causal flash attention ----------
// grid (32 q-tiles, 32 b*h), 256 threads. BQ=BKV=64. Wave w owns q rows [qt*64+w*16, +16).
__global__ __launch_bounds__(256)
void mla_attn(const ushort* __restrict__ q, const ushort* __restrict__ kvb,
              const ushort* __restrict__ kpe, ushort* __restrict__ out, float scale) {
    __shared__ ushort sK[64][200];   // 192 + 8 pad (16B-aligned rows, 2-way banks = free)
    __shared__ ushort sVt[128][72];  // V transposed: [d][kv], 64 + 8 pad
    __shared__ ushort sP[4][16][72]; // per-wave P: [qrow][kv], 64 + 8 pad
    const int tid = threadIdx.x, wave = tid >> 6, lane = tid & 63;
    const int qt = blockIdx.x;
    const int b = blockIdx.y >> 4, h = blockIdx.y & 15;

    const int qrow = qt * 64 + wave * 16 + (lane & 15);
    const ushort* qp = q + ((size_t)(b * 2048 + qrow) * 16 + h) * 192 + (lane >> 4) * 8;
    short8 qf[6];
#pragma unroll
    for (int c = 0; c < 6; ++c) qf[c] = *(const short8*)(qp + c * 32);

    float4v oacc[8] = {};
    float m_i[4] = {-INFINITY, -INFINITY, -INFINITY, -INFINITY};
    float l_i[4] = {0.f, 0.f, 0.f, 0.f};
    const int myrow0 = qt * 64 + wave * 16 + (lane >> 4) * 4;

    for (int kt = 0; kt <= qt; ++kt) {
        // stage K tile (64 x 192): 128 from k_nope (kvb), 64 from shared k_pe
#pragma unroll
        for (int t = 0; t < 6; ++t) {
            int ci = t * 256 + tid;
            int r = ci / 24, cp = ci % 24;
            int s = kt * 64 + r;
            short8 v;
            if (cp < 16) v = *(const short8*)(kvb + ((size_t)(b * 2048 + s) * 16 + h) * 256 + cp * 8);
            else         v = *(const short8*)(kpe + (size_t)(b * 2048 + s) * 64 + (cp - 16) * 8);
            *(short8*)(&sK[r][cp * 8]) = v;
        }
        // stage V^T (128 d x 64 kv)
        {
            int r = tid & 63, dh = tid >> 6;
            const ushort* vp = kvb + ((size_t)(b * 2048 + kt * 64 + r) * 16 + h) * 256 + 128 + dh * 32;
            short8 vv[4];
#pragma unroll
            for (int j = 0; j < 4; ++j) vv[j] = *(const short8*)(vp + j * 8);
#pragma unroll
            for (int j = 0; j < 4; ++j)
#pragma unroll
                for (int e = 0; e < 8; ++e)
                    sVt[dh * 32 + j * 8 + e][r] = (ushort)vv[j][e];
        }
        __syncthreads();
        // S = Q K^T (per wave: 16 x 64)
        float4v sc[4];
#pragma unroll
        for (int ct = 0; ct < 4; ++ct) {
            float4v a = {0.f, 0.f, 0.f, 0.f};
#pragma unroll
            for (int c = 0; c < 6; ++c) {
                short8 kf = *(const short8*)(&sK[ct * 16 + (lane & 15)][c * 32 + (lane >> 4) * 8]);
                a = __builtin_amdgcn_mfma_f32_16x16x32_bf16(qf[c], kf, a, 0, 0, 0);
            }
            sc[ct] = a;
        }
        // scale + causal mask + online softmax
        float mnew[4];
#pragma unroll
        for (int r = 0; r < 4; ++r) mnew[r] = m_i[r];
#pragma unroll
        for (int ct = 0; ct < 4; ++ct)
#pragma unroll
            for (int r = 0; r < 4; ++r) {
                float v = sc[ct][r] * scale;
                if (kt == qt && (kt * 64 + ct * 16 + (lane & 15)) > (myrow0 + r)) v = -INFINITY;
                sc[ct][r] = v;
                mnew[r] = fmaxf(mnew[r], v);
            }
#pragma unroll
        for (int off = 8; off >= 1; off >>= 1)
#pragma unroll
            for (int r = 0; r < 4; ++r) mnew[r] = fmaxf(mnew[r], __shfl_xor(mnew[r], off));
        float alpha[4], psum[4];
#pragma unroll
        for (int r = 0; r < 4; ++r) {
            alpha[r] = __expf(m_i[r] - mnew[r]);
            m_i[r] = mnew[r];
            psum[r] = 0.f;
        }
#pragma unroll
        for (int ct = 0; ct < 4; ++ct)
#pragma unroll
            for (int r = 0; r < 4; ++r) {
                float pv = __expf(sc[ct][r] - mnew[r]);
                psum[r] += pv;
                sP[wave][(lane >> 4) * 4 + r][ct * 16 + (lane & 15)] = f2b(pv);
            }
#pragma unroll
        for (int off = 8; off >= 1; off >>= 1)
#pragma unroll
            for (int r = 0; r < 4; ++r) psum[r] += __shfl_xor(psum[r], off);
#pragma unroll
        for (int r = 0; r < 4; ++r) l_i[r] = l_i[r] * alpha[r] + psum[r];
#pragma unroll
        for (int dt = 0; dt < 8; ++dt)
#pragma unroll
            for (int r = 0; r < 4; ++r) oacc[dt][r] *= alpha[r];
        // ensure sP visible across lanes before MFMA reads (cross-lane via LDS)
        __syncthreads();
        // O += P @ V
#pragma unroll
        for (int kc = 0; kc < 2; ++kc) {
            short8 pf = *(const short8*)(&sP[wave][lane & 15][kc * 32 + (lane >> 4) * 8]);
#pragma unroll
            for (int dt = 0; dt < 8; ++dt) {
                short8 vf = *(const short8*)(&sVt[dt * 16 + (lane & 15)][kc * 32 + (lane >> 4) * 8]);
                oacc[dt] = __builtin_amdgcn_mfma_f32_16x16x32_bf16(pf, vf, oacc[dt], 0, 0, 0);
            }
        }
        __syncthreads();
    }
#pragma unroll
    for (int dt = 0; dt < 8; ++dt) {
#pragma unroll
        for (int r = 0; r < 4; ++r) {
            int row = myrow0 + r;
            out[((size_t)(b * 2048 + row) * 16 + h) * 128 + dt * 16 + (lane & 15)] =
                f2b(oacc[dt][r] / l_i[r]);
        }
    }
}

// ---------- launch ----------
extern "C" void kernel_launch(void* const* d_in, const int* in_sizes, int n_in,
                              void* d_out, int out_size, void* d_ws, size_t ws_size,
                              hipStream_t stream) {
    const float* x     = (const float*)d_in[0];
    // d_in[1] = start_pos (0, unused by reference math)
    const float* freqs = (const float*)d_in[2];
    const float* wq_a  = (const float*)d_in[3];
    const float* qnw   = (const float*)d_in[4];
    const float* wq_b  = (const float*)d_in[5];
    const float* wkv_a = (const float*)d_in[6];
    const float* kvnw  = (const float*)d_in[7];
    const float* wkv_b = (const float*)d_in[8];
    const float* wo    = (const float*)d_in[9];

    char* ws = (char*)d_ws;
    size_t off = 0;
    auto alloc = [&](size_t n) { char* p = ws + off; off += (n + 255) & ~(size_t)255; return p; };
    ushort* xb    = (ushort*)alloc(4096ull * 2048 * 2);
    ushort* wqab  = (ushort*)alloc(1536ull * 2048 * 2);
    ushort* wqbb  = (ushort*)alloc(3072ull * 1536 * 2);
    ushort* wkvab = (ushort*)alloc(640ull * 2048 * 2);   // padded 576->640 rows
    ushort* wkvbb = (ushort*)alloc(4096ull * 512 * 2);
    ushort* wob   = (ushort*)alloc(2048ull * 2048 * 2);
    ushort* qa    = (ushort*)alloc(4096ull * 1536 * 2);
    ushort* kvraw = (ushort*)alloc(4096ull * 576 * 2);
    ushort* kvc   = (ushort*)alloc(4096ull * 512 * 2);
    ushort* kpe   = (ushort*)alloc(4096ull * 64 * 2);
    ushort* qfull = (ushort*)alloc(4096ull * 3072 * 2);
    ushort* kvbuf = (ushort*)alloc(4096ull * 4096 * 2);
    ushort* attno = (ushort*)alloc(4096ull * 2048 * 2);
    if (off > ws_size) return;  // workspace too small -> fails with absmax == max|ref|

    auto cvt = [&](const float* s, ushort* dd, int sr, int cols, size_t dtot) {
        int t4 = (int)(dtot / 4);
        cvt_pad<<<(t4 + 255) / 256, 256, 0, stream>>>(s, dd, sr, cols, t4);
    };
    cvt(x, xb, 4096, 2048, 4096ull * 2048);
    cvt(wq_a, wqab, 1536, 2048, 1536ull * 2048);
    cvt(wq_b, wqbb, 3072, 1536, 3072ull * 1536);
    cvt(wkv_a, wkvab, 576, 2048, 640ull * 2048);
    cvt(wkv_b, wkvbb, 4096, 512, 4096ull * 512);
    cvt(wo, wob, 2048, 2048, 2048ull * 2048);

    gemm_bt<<<dim3(12, 32), 256, 0, stream>>>(xb, wqab, qa, 2048, 1536, 1536, 0);
    gemm_bt<<<dim3(5, 32), 256, 0, stream>>>(xb, wkvab, kvraw, 2048, 576, 576, 0);
    rmsnorm_inplace<<<4096, 256, 0, stream>>>(qa, qnw, 1536);
    kvnorm_rope<<<4096, 256, 0, stream>>>(kvraw, kvnw, freqs, kvc, kpe);
    gemm_bt<<<dim3(24, 32), 256, 0, stream>>>(qa, wqbb, qfull, 1536, 3072, 3072, 0);
    qrope<<<8192, 256, 0, stream>>>(qfull, freqs);
    gemm_bt<<<dim3(32, 32), 256, 0, stream>>>(kvc, wkvbb, kvbuf, 512, 4096, 4096, 0);
    const float scale = 1.0f / sqrtf(192.0f);
    mla_attn<<<dim3(32, 32), 256, 0, stream>>>(qfull, kvbuf, kpe, attno, scale);
    gemm_bt<<<dim3(16, 32), 256, 0, stream>>>(attno, wob, (float*)d_out, 2048, 2048, 2048, 1);
}

// Round 3
// 550.202 us; speedup vs baseline: 1.1982x; 1.1982x over previous
//
#include <hip/hip_runtime.h>
#include <math.h>

typedef short short8 __attribute__((ext_vector_type(8)));
typedef float float4v __attribute__((ext_vector_type(4)));
#define AS1 __attribute__((address_space(1)))
#define AS3 __attribute__((address_space(3)))

__device__ __forceinline__ float b2f(ushort u) {
    unsigned v = ((unsigned)u) << 16; float f; __builtin_memcpy(&f, &v, 4); return f;
}
__device__ __forceinline__ ushort f2b(float f) {
    unsigned v; __builtin_memcpy(&v, &f, 4);
    unsigned r = (v + 0x7fffu + ((v >> 16) & 1u)) >> 16;
    return (ushort)r;
}

// ---------- fp32 -> bf16 convert (optional zero-pad rows) ----------
__global__ void cvt_pad(const float* __restrict__ src, ushort* __restrict__ dst,
                        int src_rows, int cols, int total4) {
    int i = blockIdx.x * 256 + threadIdx.x;
    if (i >= total4) return;
    size_t e = (size_t)i * 4;
    int r = (int)(e / (size_t)cols);
    ushort4 o;
    if (r < src_rows) {
        float4 v = *(const float4*)(src + e);
        o.x = f2b(v.x); o.y = f2b(v.y); o.z = f2b(v.z); o.w = f2b(v.w);
    } else {
        o.x = 0; o.y = 0; o.z = 0; o.w = 0;
    }
    *(ushort4*)(dst + e) = o;
}

// ---------- bf16 GEMM: C(MxN) = A(MxK) @ B(NxK)^T ----------
__global__ __launch_bounds__(256)
void gemm_bt(const ushort* __restrict__ A, const ushort* __restrict__ B,
             void* __restrict__ Cv, int K, int ldc, int nstore, int f32out) {
    __shared__ ushort sA[128 * 32];
    __shared__ ushort sB[128 * 32];
    const int tid = threadIdx.x;
    const int wave = tid >> 6, lane = tid & 63;
    const int bm = blockIdx.y * 128, bn = blockIdx.x * 128;
    const int wm = (wave >> 1) * 64, wn = (wave & 1) * 64;
    float4v acc[4][4] = {};

    const int srow = wave * 32 + (lane >> 2);
    const int skc = (lane & 3) * 8;
    const ushort* Ag = A + (size_t)(bm + srow) * K + skc;
    const ushort* Bg = B + (size_t)(bn + srow) * K + skc;
    ushort* sAw = sA + (wave * 32) * 32;
    ushort* sBw = sB + (wave * 32) * 32;

    for (int k0 = 0; k0 < K; k0 += 32) {
        __builtin_amdgcn_global_load_lds((const AS1 void*)(Ag + k0), (AS3 void*)sAw, 16, 0, 0);
        __builtin_amdgcn_global_load_lds((const AS1 void*)(Ag + (size_t)16 * K + k0),
                                         (AS3 void*)(sAw + 16 * 32), 16, 0, 0);
        __builtin_amdgcn_global_load_lds((const AS1 void*)(Bg + k0), (AS3 void*)sBw, 16, 0, 0);
        __builtin_amdgcn_global_load_lds((const AS1 void*)(Bg + (size_t)16 * K + k0),
                                         (AS3 void*)(sBw + 16 * 32), 16, 0, 0);
        __syncthreads();
        short8 af[4], bfr[4];
#pragma unroll
        for (int i = 0; i < 4; ++i) {
            af[i]  = *(const short8*)(sA + (wm + i * 16 + (lane & 15)) * 32 + (lane >> 4) * 8);
            bfr[i] = *(const short8*)(sB + (wn + i * 16 + (lane & 15)) * 32 + (lane >> 4) * 8);
        }
#pragma unroll
        for (int i = 0; i < 4; ++i)
#pragma unroll
            for (int j = 0; j < 4; ++j)
                acc[i][j] = __builtin_amdgcn_mfma_f32_16x16x32_bf16(af[i], bfr[j], acc[i][j], 0, 0, 0);
        __syncthreads();
    }
#pragma unroll
    for (int i = 0; i < 4; ++i) {
        int row0 = bm + wm + i * 16 + (lane >> 4) * 4;
#pragma unroll
        for (int j = 0; j < 4; ++j) {
            int col = bn + wn + j * 16 + (lane & 15);
            if (col < nstore) {
                if (f32out) {
                    float* C = (float*)Cv;
#pragma unroll
                    for (int r = 0; r < 4; ++r)
                        C[(size_t)(row0 + r) * ldc + col] = acc[i][j][r];
                } else {
                    ushort* C = (ushort*)Cv;
#pragma unroll
                    for (int r = 0; r < 4; ++r)
                        C[(size_t)(row0 + r) * ldc + col] = f2b(acc[i][j][r]);
                }
            }
        }
    }
}

// ---------- rmsnorm (in-place, one block per row) ----------
__global__ void rmsnorm_inplace(ushort* __restrict__ d, const float* __restrict__ w, int cols) {
    int row = blockIdx.x, tid = threadIdx.x;
    ushort* p = d + (size_t)row * cols;
    float ss = 0.f;
    for (int i = tid; i < cols; i += 256) { float v = b2f(p[i]); ss += v * v; }
#pragma unroll
    for (int off = 32; off >= 1; off >>= 1) ss += __shfl_xor(ss, off);
    __shared__ float red[4];
    if ((tid & 63) == 0) red[tid >> 6] = ss;
    __syncthreads();
    float tot = red[0] + red[1] + red[2] + red[3];
    float rs = rsqrtf(tot / (float)cols + 1e-6f);
    for (int i = tid; i < cols; i += 256) p[i] = f2b(b2f(p[i]) * rs * w[i]);
}

// ---------- kv norm (cols 0..512) + k_pe rope (cols 512..576) ----------
__global__ void kvnorm_rope(const ushort* __restrict__ kvraw, const float* __restrict__ w,
                            const float* __restrict__ freqs, ushort* __restrict__ kvc,
                            ushort* __restrict__ kpe) {
    int row = blockIdx.x, tid = threadIdx.x;
    int s = row & 2047;
    const ushort* p = kvraw + (size_t)row * 576;
    float v0 = b2f(p[tid]), v1 = b2f(p[tid + 256]);
    float ss = v0 * v0 + v1 * v1;
#pragma unroll
    for (int off = 32; off >= 1; off >>= 1) ss += __shfl_xor(ss, off);
    __shared__ float red[4];
    if ((tid & 63) == 0) red[tid >> 6] = ss;
    __syncthreads();
    float tot = red[0] + red[1] + red[2] + red[3];
    float rs = rsqrtf(tot / 512.f + 1e-6f);
    kvc[(size_t)row * 512 + tid] = f2b(v0 * rs * w[tid]);
    kvc[(size_t)row * 512 + tid + 256] = f2b(v1 * rs * w[tid + 256]);
    if (tid < 32) {
        float re = b2f(p[512 + 2 * tid]), im = b2f(p[512 + 2 * tid + 1]);
        float cs = freqs[(s * 32 + tid) * 2], sn = freqs[(s * 32 + tid) * 2 + 1];
        kpe[(size_t)row * 64 + 2 * tid] = f2b(re * cs - im * sn);
        kpe[(size_t)row * 64 + 2 * tid + 1] = f2b(re * sn + im * cs);
    }
}

// ---------- rope on q_pe (last 64 of each 192-dim head) ----------
__global__ void qrope(ushort* __restrict__ q, const float* __restrict__ freqs) {
    int idx = blockIdx.x * 256 + threadIdx.x;
    int i = idx & 31;
    int h = (idx >> 5) & 15;
    int srow = idx >> 9;
    int s = srow & 2047;
    ushort* p = q + ((size_t)srow * 16 + h) * 192 + 128 + 2 * i;
    float re = b2f(p[0]), im = b2f(p[1]);
    float cs = freqs[(s * 32 + i) * 2], sn = freqs[(s * 32 + i) * 2 + 1];
    p[0] = f2b(re * cs - im * sn);
    p[1] = f2b(re * sn + im * cs);
}

// ---------- K repack: Kfull[b][h][s][200] = k_nope(128) | k_pe(64) | pad(8) ----------
// 8 rows per block of 256 threads; 32 lanes per row (25 active).
__global__ void k_repack(const ushort* __restrict__ kvb, const ushort* __restrict__ kpe,
                         ushort* __restrict__ Kfull) {
    int tid = threadIdx.x;
    int row = blockIdx.x * 8 + (tid >> 5);   // row = bh*2048 + s
    int c = tid & 31;
    int bh = row >> 11, s = row & 2047;
    int b = bh >> 4, h = bh & 15;
    size_t sg = (size_t)b * 2048 + s;
    short8 v = {0, 0, 0, 0, 0, 0, 0, 0};
    if (c < 16)      v = *(const short8*)(kvb + sg * 4096 + h * 256 + c * 8);
    else if (c < 24) v = *(const short8*)(kpe + sg * 64 + (c - 16) * 8);
    if (c < 25) *(short8*)(Kfull + (size_t)row * 200 + c * 8) = v;
}

// ---------- V repack/transpose: Vt[bh][kt][128][72] (cols 64..71 pad) ----------
__global__ __launch_bounds__(256)
void v_repack(const ushort* __restrict__ kvb, ushort* __restrict__ Vt) {
    __shared__ ushort sT[64][136];
    int tid = threadIdx.x;
    int kt = blockIdx.x, bh = blockIdx.y;
    int b = bh >> 4, h = bh & 15;
#pragma unroll
    for (int k = 0; k < 4; ++k) {
        int id = k * 256 + tid;          // 0..1023
        int r = id >> 4, c8 = id & 15;
        size_t sg = (size_t)b * 2048 + kt * 64 + r;
        *(short8*)(&sT[r][c8 * 8]) = *(const short8*)(kvb + sg * 4096 + h * 256 + 128 + c8 * 8);
    }
    __syncthreads();
    int d = tid >> 1, half = tid & 1;
    ushort tmp[32];
#pragma unroll
    for (int i = 0; i < 32; ++i) tmp[i] = sT[half * 32 + i][d];
    ushort* dst = Vt + (((size_t)bh * 32 + kt) * 128 + d) * 72 + half * 32;
#pragma unroll
    for (int i = 0; i < 4; ++i) *(short8*)(dst + i * 8) = *(const short8*)(tmp + i * 8);
}

// ---------- causal flash attention, paired q-tiles ----------
// grid (16 pairs, 32 bh). Block p: phase 0 -> qt=31-p, phase 1 -> qt=p (33 iters total).
__global__ __launch_bounds__(256)
void mla_attn2(const ushort* __restrict__ q, const ushort* __restrict__ Kfull,
               const ushort* __restrict__ Vt, ushort* __restrict__ out, float scale) {
    __shared__ ushort sK[64 * 200];
    __shared__ ushort sV[128 * 72];
    __shared__ ushort sP[4][16][72];
    const int tid = threadIdx.x, wave = tid >> 6, lane = tid & 63;
    const int p = blockIdx.x, bh = blockIdx.y;
    const int b = bh >> 4, h = bh & 15;
    const ushort* Kb = Kfull + (size_t)bh * 2048 * 200;
    const ushort* Vb = Vt + (size_t)bh * 32 * 128 * 72;

    for (int phase = 0; phase < 2; ++phase) {
        const int qt = (phase == 0) ? (31 - p) : p;
        const int qrow = qt * 64 + wave * 16 + (lane & 15);
        const ushort* qp = q + ((size_t)(b * 2048 + qrow) * 16 + h) * 192 + (lane >> 4) * 8;
        short8 qf[6];
#pragma unroll
        for (int c = 0; c < 6; ++c) qf[c] = *(const short8*)(qp + c * 32);

        float4v oacc[8] = {};
        float m_i[4] = {-INFINITY, -INFINITY, -INFINITY, -INFINITY};
        float l_i[4] = {0.f, 0.f, 0.f, 0.f};
        const int myrow0 = qt * 64 + wave * 16 + (lane >> 4) * 4;

        for (int kt = 0; kt <= qt; ++kt) {
            const ushort* Ksrc = Kb + (size_t)kt * 64 * 200;   // contiguous 25600 B
            const ushort* Vsrc = Vb + (size_t)kt * 128 * 72;   // contiguous 18432 B
#pragma unroll
            for (int i = 0; i < 7; ++i) {                       // 1600 slots of 16 B
                int s0 = i * 256 + wave * 64;
                if (s0 < 1600)
                    __builtin_amdgcn_global_load_lds(
                        (const AS1 void*)(Ksrc + (size_t)(s0 + lane) * 8),
                        (AS3 void*)(sK + s0 * 8), 16, 0, 0);
            }
#pragma unroll
            for (int i = 0; i < 5; ++i) {                       // 1152 slots of 16 B
                int s0 = i * 256 + wave * 64;
                if (s0 < 1152)
                    __builtin_amdgcn_global_load_lds(
                        (const AS1 void*)(Vsrc + (size_t)(s0 + lane) * 8),
                        (AS3 void*)(sV + s0 * 8), 16, 0, 0);
            }
            __syncthreads();
            // S = Q K^T (per wave: 16 x 64)
            float4v sc[4];
#pragma unroll
            for (int ct = 0; ct < 4; ++ct) {
                float4v a = {0.f, 0.f, 0.f, 0.f};
#pragma unroll
                for (int c = 0; c < 6; ++c) {
                    short8 kf = *(const short8*)(sK + (ct * 16 + (lane & 15)) * 200 + c * 32 + (lane >> 4) * 8);
                    a = __builtin_amdgcn_mfma_f32_16x16x32_bf16(qf[c], kf, a, 0, 0, 0);
                }
                sc[ct] = a;
            }
            // scale + causal mask + online softmax
            float mnew[4];
#pragma unroll
            for (int r = 0; r < 4; ++r) mnew[r] = m_i[r];
#pragma unroll
            for (int ct = 0; ct < 4; ++ct)
#pragma unroll
                for (int r = 0; r < 4; ++r) {
                    float v = sc[ct][r] * scale;
                    if (kt == qt && (kt * 64 + ct * 16 + (lane & 15)) > (myrow0 + r)) v = -INFINITY;
                    sc[ct][r] = v;
                    mnew[r] = fmaxf(mnew[r], v);
                }
#pragma unroll
            for (int off = 8; off >= 1; off >>= 1)
#pragma unroll
                for (int r = 0; r < 4; ++r) mnew[r] = fmaxf(mnew[r], __shfl_xor(mnew[r], off));
            float alpha[4], psum[4];
#pragma unroll
            for (int r = 0; r < 4; ++r) {
                alpha[r] = __expf(m_i[r] - mnew[r]);
                m_i[r] = mnew[r];
                psum[r] = 0.f;
            }
#pragma unroll
            for (int ct = 0; ct < 4; ++ct)
#pragma unroll
                for (int r = 0; r < 4; ++r) {
                    float pv = __expf(sc[ct][r] - mnew[r]);
                    psum[r] += pv;
                    sP[wave][(lane >> 4) * 4 + r][ct * 16 + (lane & 15)] = f2b(pv);
                }
#pragma unroll
            for (int off = 8; off >= 1; off >>= 1)
#pragma unroll
                for (int r = 0; r < 4; ++r) psum[r] += __shfl_xor(psum[r], off);
#pragma unroll
            for (int r = 0; r < 4; ++r) l_i[r] = l_i[r] * alpha[r] + psum[r];
#pragma unroll
            for (int dt = 0; dt < 8; ++dt)
#pragma unroll
                for (int r = 0; r < 4; ++r) oacc[dt][r] *= alpha[r];
            __syncthreads();
            // O += P @ V
#pragma unroll
            for (int kc = 0; kc < 2; ++kc) {
                short8 pf = *(const short8*)(&sP[wave][lane & 15][kc * 32 + (lane >> 4) * 8]);
#pragma unroll
                for (int dt = 0; dt < 8; ++dt) {
                    short8 vf = *(const short8*)(sV + (dt * 16 + (lane & 15)) * 72 + kc * 32 + (lane >> 4) * 8);
                    oacc[dt] = __builtin_amdgcn_mfma_f32_16x16x32_bf16(pf, vf, oacc[dt], 0, 0, 0);
                }
            }
            __syncthreads();
        }
#pragma unroll
        for (int dt = 0; dt < 8; ++dt) {
#pragma unroll
            for (int r = 0; r < 4; ++r) {
                int row = myrow0 + r;
                out[((size_t)(b * 2048 + row) * 16 + h) * 128 + dt * 16 + (lane & 15)] =
                    f2b(oacc[dt][r] / l_i[r]);
            }
        }
    }
}

// ---------- launch ----------
extern "C" void kernel_launch(void* const* d_in, const int* in_sizes, int n_in,
                              void* d_out, int out_size, void* d_ws, size_t ws_size,
                              hipStream_t stream) {
    const float* x     = (const float*)d_in[0];
    const float* freqs = (const float*)d_in[2];
    const float* wq_a  = (const float*)d_in[3];
    const float* qnw   = (const float*)d_in[4];
    const float* wq_b  = (const float*)d_in[5];
    const float* wkv_a = (const float*)d_in[6];
    const float* kvnw  = (const float*)d_in[7];
    const float* wkv_b = (const float*)d_in[8];
    const float* wo    = (const float*)d_in[9];

    char* ws = (char*)d_ws;
    size_t off = 0;
    auto alloc = [&](size_t n) { char* p = ws + off; off += (n + 255) & ~(size_t)255; return p; };
    ushort* xb    = (ushort*)alloc(4096ull * 2048 * 2);   // dead after q_a/kv_a gemms
    ushort* wqab  = (ushort*)alloc(1536ull * 2048 * 2);   // dead after q_a gemm
    ushort* wqbb  = (ushort*)alloc(3072ull * 1536 * 2);   // dead after q_b gemm
    ushort* wkvab = (ushort*)alloc(640ull * 2048 * 2);    // dead after kv_a gemm
    ushort* wkvbb = (ushort*)alloc(4096ull * 512 * 2);    // dead after kv_b gemm
    ushort* wob   = (ushort*)alloc(2048ull * 2048 * 2);   // live until final gemm
    ushort* qa    = (ushort*)alloc(4096ull * 1536 * 2);   // dead after q_b gemm
    ushort* kvraw = (ushort*)alloc(4096ull * 576 * 2);    // dead after kvnorm_rope
    ushort* kvc   = (ushort*)alloc(4096ull * 512 * 2);    // dead after kv_b gemm
    ushort* kpe   = (ushort*)alloc(4096ull * 64 * 2);
    ushort* qfull = (ushort*)alloc(4096ull * 3072 * 2);
    ushort* kvbuf = (ushort*)alloc(4096ull * 4096 * 2);
    ushort* attno = (ushort*)alloc(4096ull * 2048 * 2);
    if (off > ws_size) return;
    // Aliased late buffers over dead regions:
    // Kfull: 26,214,400 B over xb..wkvbb (39,321,600 B) -- wob untouched.
    ushort* Kfull = (ushort*)xb;
    // Vt: 18,874,368 B over qa..kvc (21,495,808 B) -- kpe untouched.
    ushort* Vt = (ushort*)qa;

    auto cvt = [&](const float* s, ushort* dd, int sr, int cols, size_t dtot) {
        int t4 = (int)(dtot / 4);
        cvt_pad<<<(t4 + 255) / 256, 256, 0, stream>>>(s, dd, sr, cols, t4);
    };
    cvt(x, xb, 4096, 2048, 4096ull * 2048);
    cvt(wq_a, wqab, 1536, 2048, 1536ull * 2048);
    cvt(wq_b, wqbb, 3072, 1536, 3072ull * 1536);
    cvt(wkv_a, wkvab, 576, 2048, 640ull * 2048);
    cvt(wkv_b, wkvbb, 4096, 512, 4096ull * 512);
    cvt(wo, wob, 2048, 2048, 2048ull * 2048);

    gemm_bt<<<dim3(12, 32), 256, 0, stream>>>(xb, wqab, qa, 2048, 1536, 1536, 0);
    gemm_bt<<<dim3(5, 32), 256, 0, stream>>>(xb, wkvab, kvraw, 2048, 576, 576, 0);
    rmsnorm_inplace<<<4096, 256, 0, stream>>>(qa, qnw, 1536);
    kvnorm_rope<<<4096, 256, 0, stream>>>(kvraw, kvnw, freqs, kvc, kpe);
    gemm_bt<<<dim3(24, 32), 256, 0, stream>>>(qa, wqbb, qfull, 1536, 3072, 3072, 0);
    qrope<<<8192, 256, 0, stream>>>(qfull, freqs);
    gemm_bt<<<dim3(32, 32), 256, 0, stream>>>(kvc, wkvbb, kvbuf, 512, 4096, 4096, 0);
    // ---- repack (xb/wq*/wkv* and qa/kvraw/kvc are dead from here) ----
    k_repack<<<8192, 256, 0, stream>>>(kvbuf, kpe, Kfull);
    v_repack<<<dim3(32, 32), 256, 0, stream>>>(kvbuf, Vt);
    const float scale = 1.0f / sqrtf(192.0f);
    mla_attn2<<<dim3(16, 32), 256, 0, stream>>>(qfull, Kfull, Vt, attno, scale);
    gemm_bt<<<dim3(16, 32), 256, 0, stream>>>(attno, wob, (float*)d_out, 2048, 2048, 2048, 1);
}